// Round 9
// baseline (2283.287 us; speedup 1.0000x reference)
//
#include <hip/hip_runtime.h>

#define HH 56
#define WW 56
#define CC 512
#define BB 32
#define LL (HH*WW)
#define MM (BB*LL)     // 100352 tokens
#define HID 2048

typedef __attribute__((ext_vector_type(8))) __bf16 bf16x8;
typedef __attribute__((ext_vector_type(4))) float f32x4;
typedef __attribute__((ext_vector_type(4))) short s16x4;

__device__ __forceinline__ short f2bf(float f) {
    union { float f; unsigned u; } c; c.f = f;
    unsigned r = c.u + 0x7fffu + ((c.u >> 16) & 1u);   // round-to-nearest-even
    return (short)(r >> 16);
}
__device__ __forceinline__ float bf2f(short s) {
    union { unsigned u; float f; } c; c.u = ((unsigned)(unsigned short)s) << 16;
    return c.f;
}

// fast gelu: v * t/(t+1), t = e^{2*0.7978845608*(v+0.044715 v^3)}
__device__ __forceinline__ float gelu_fast(float v) {
    float xg = 0.7978845608f * (v + 0.044715f * v * v * v);
    xg = fminf(xg, 15.0f);
    float t = __expf(2.0f * xg);
    return v * (t / (t + 1.0f));
}

// ---------------- f32 -> bf16 weight conversion ----------------
__global__ __launch_bounds__(256) void cvt_bf16(const float* __restrict__ in,
                                                short* __restrict__ out, int n) {
    int i = blockIdx.x * 256 + threadIdx.x;
    if (i < n) out[i] = f2bf(in[i]);
}

// ---------------- LayerNorm over 512 channels, 1 row / block ----------------
__global__ __launch_bounds__(256) void ln512(const float* __restrict__ x,
                                             const float* __restrict__ g,
                                             const float* __restrict__ b,
                                             short* __restrict__ out) {
    const int row = blockIdx.x;
    const int t = threadIdx.x;
    const float2 v = ((const float2*)(x + (long)row * 512))[t];
    float s = v.x + v.y;
    float q = v.x * v.x + v.y * v.y;
#pragma unroll
    for (int off = 32; off > 0; off >>= 1) {
        s += __shfl_xor(s, off, 64);
        q += __shfl_xor(q, off, 64);
    }
    __shared__ float red[8];
    const int wv = t >> 6;
    if ((t & 63) == 0) { red[wv] = s; red[4 + wv] = q; }
    __syncthreads();
    s = red[0] + red[1] + red[2] + red[3];
    q = red[4] + red[5] + red[6] + red[7];
    const float mu = s * (1.0f / 512.0f);
    const float rs = rsqrtf(q * (1.0f / 512.0f) - mu * mu + 1e-5f);
    const float2 gv = ((const float2*)g)[t];
    const float2 bv = ((const float2*)b)[t];
    const float y0 = (v.x - mu) * rs * gv.x + bv.x;
    const float y1 = (v.y - mu) * rs * gv.y + bv.y;
    union { short s2[2]; unsigned u; } o;
    o.s2[0] = f2bf(y0); o.s2[1] = f2bf(y1);
    ((unsigned*)out)[(long)row * 256 + t] = o.u;
}

// ---------------- spatial (window) MLP + residual ----------------
__global__ __launch_bounds__(256) void spatial_mlp(const short* __restrict__ xn,
                                                   const float* __restrict__ x,
                                                   const float* __restrict__ sw,
                                                   const float* __restrict__ sb,
                                                   float* x1) {
    const int head = blockIdx.y;
    const int t = threadIdx.x;
    const int ch = t & 31;
    const int wloc = t >> 5;
    const int win = blockIdx.x * 8 + wloc;        // 0..2591
    const int b = win / 81;
    const int rr = win - b * 81;
    const int wi = rr / 9;
    const int wj = rr - wi * 9;
    const int c = head * 32 + ch;

    float xv[49];
#pragma unroll
    for (int j = 0; j < 49; j++) {
        const int pr = wi * 7 + j / 7 - 4;        // padded row - P_T
        const int pc = wj * 7 + j % 7 - 4;        // padded col - P_L
        float v = 0.0f;
        if (pr >= 0 && pr < 56 && pc >= 0 && pc < 56)
            v = bf2f(xn[((long)((b * 56 + pr) * 56 + pc)) * 512 + c]);
        xv[j] = v;
    }

    const float* swh = sw + head * 2401;
    const float* sbh = sb + head * 49;

#pragma unroll 1
    for (int t7 = 0; t7 < 7; t7++) {
        float acc[7];
#pragma unroll
        for (int ii = 0; ii < 7; ii++) acc[ii] = sbh[t7 * 7 + ii];
#pragma unroll
        for (int ii = 0; ii < 7; ii++) {
            const float* swr = swh + (t7 * 7 + ii) * 49;
#pragma unroll
            for (int j = 0; j < 49; j++)
                acc[ii] = fmaf(swr[j], xv[j], acc[ii]);
        }
        const int pr = wi * 7 + t7 - 4;
        if (pr >= 0 && pr < 56) {
#pragma unroll
            for (int ii = 0; ii < 7; ii++) {
                const int pc = wj * 7 + ii - 4;
                if (pc >= 0 && pc < 56) {
                    const long idx = ((long)((b * 56 + pr) * 56 + pc)) * 512 + c;
                    x1[idx] = x[idx] + acc[ii];
                }
            }
        }
    }
}

// ---------------- 128x128 4-wave bf16 GEMM, ring-3 counted-vmcnt -------------
// r5's exact structure + ABL ablation axis (within-probe A/B, rule 19 noted):
//   ABL=0 full | ABL=1 stage+barriers only | ABL=2 +ds_read (no MFMA) |
//   ABL=3 +MFMA (no ds_read, frags from regs)
template <int K, int N, bool GELU, int ABL>
__global__ __launch_bounds__(256, 3) void gemm128(const short* __restrict__ A,
                                                  const short* __restrict__ Bw,
                                                  const float* __restrict__ bias,
                                                  const float* res,
                                                  void* Cout) {
    __shared__ __attribute__((aligned(16))) short S[24576];  // 48 KB
    const int tid = threadIdx.x;
    const int lane = tid & 63;
    const int wid = tid >> 6;
    const int wr = wid >> 1;          // 0..1  M-half (64 rows)
    const int wc = wid & 1;           // 0..1  N-half (64 cols)
    const int lr = lane & 15;
    const int kg = (lane >> 4) & 3;

    // T1: bijective XCD-aware remap (nwg % 8 == 0)
    const int gx = gridDim.x;
    const int lin = blockIdx.y * gx + blockIdx.x;
    const int cpx = (gx * gridDim.y) >> 3;
    const int orig = (lin & 7) * cpx + (lin >> 3);
    const long mBase = (long)(orig / gx) * 128;
    const long nBase = (long)(orig % gx) * 128;

    // staging source (per-thread, fixed): pre-swizzled K-chunk (key=(row>>1)&3)
    const int sRow = tid >> 2;                        // 0..63
    const int sChunk = (tid & 3) ^ ((tid >> 3) & 3);
    const short* aSrc0 = A + (mBase + sRow) * K + sChunk * 8;
    const short* aSrc1 = A + (mBase + 64 + sRow) * K + sChunk * 8;
    const short* bSrc0 = Bw + (nBase + sRow) * K + sChunk * 8;
    const short* bSrc1 = Bw + (nBase + 64 + sRow) * K + sChunk * 8;

    auto stage = [&](int buf, int t) {
        const long k0 = (long)t * 32;
        char* Ad = (char*)S + buf * 8192 + tid * 16;
        char* Bd = (char*)S + 24576 + buf * 8192 + tid * 16;
        __builtin_amdgcn_global_load_lds(
            (const __attribute__((address_space(1))) void*)(aSrc0 + k0),
            (__attribute__((address_space(3))) void*)Ad, 16, 0, 0);
        __builtin_amdgcn_global_load_lds(
            (const __attribute__((address_space(1))) void*)(aSrc1 + k0),
            (__attribute__((address_space(3))) void*)(Ad + 4096), 16, 0, 0);
        __builtin_amdgcn_global_load_lds(
            (const __attribute__((address_space(1))) void*)(bSrc0 + k0),
            (__attribute__((address_space(3))) void*)Bd, 16, 0, 0);
        __builtin_amdgcn_global_load_lds(
            (const __attribute__((address_space(1))) void*)(bSrc1 + k0),
            (__attribute__((address_space(3))) void*)(Bd + 4096), 16, 0, 0);
    };

    // fragment LDS byte offsets: row*64 + swizzled-chunk*16, key=(row>>1)&3
    const int swzc = kg ^ ((lr >> 1) & 3);
    const int aOff = (wr * 64 + lr) * 64 + swzc * 16;    // + m*1024, m=0..3
    const int bOff = (wc * 64 + lr) * 64 + swzc * 16;    // + n*1024, n=0..3

    f32x4 acc[4][4] = {};

    stage(0, 0); stage(1, 1);
    asm volatile("s_waitcnt vmcnt(4)" ::: "memory");     // tile 0 landed
    __builtin_amdgcn_s_barrier();

    const int NT = K / 32;
    int cb = 0;                                          // current ring slot
    for (int t = 0; t < NT; ++t) {
        if (t + 2 < NT) {
            const int sb = cb >= 1 ? cb - 1 : 2;         // (cb+2)%3
            stage(sb, t + 2);
        }
        const char* Ab = (const char*)S + cb * 8192;
        const char* Bb = (const char*)S + 24576 + cb * 8192;
        bf16x8 af[4], bf[4];
        if constexpr (ABL == 0 || ABL == 2) {            // ds_read path
#pragma unroll
            for (int m = 0; m < 4; ++m) af[m] = *(const bf16x8*)(Ab + aOff + m * 1024);
#pragma unroll
            for (int n = 0; n < 4; ++n) bf[n] = *(const bf16x8*)(Bb + bOff + n * 1024);
        } else if constexpr (ABL == 3) {                 // frags from cheap regs
#pragma unroll
            for (int m = 0; m < 4; ++m)
                af[m] = __builtin_bit_cast(bf16x8, (f32x4){(float)(tid + m), 0.f, 0.f, 0.f});
#pragma unroll
            for (int n = 0; n < 4; ++n)
                bf[n] = __builtin_bit_cast(bf16x8, (f32x4){(float)(tid - n), 0.f, 0.f, 0.f});
        }
        asm volatile("s_waitcnt lgkmcnt(0)" ::: "memory");
        __builtin_amdgcn_s_setprio(1);
        if constexpr (ABL == 0 || ABL == 3) {            // MFMA path
#pragma unroll
            for (int m = 0; m < 4; ++m)
#pragma unroll
                for (int n = 0; n < 4; ++n)
                    acc[m][n] = __builtin_amdgcn_mfma_f32_16x16x32_bf16(bf[n], af[m],
                                                                        acc[m][n], 0, 0, 0);
        } else if constexpr (ABL == 2) {                 // keep frags live
#pragma unroll
            for (int m = 0; m < 4; ++m) {
                f32x4 ka = __builtin_bit_cast(f32x4, af[m]);
                f32x4 kb = __builtin_bit_cast(f32x4, bf[m]);
                asm volatile("" :: "v"(ka), "v"(kb));
            }
        }
        __builtin_amdgcn_s_setprio(0);
        // boundary: buf[t+1] landed before next tile reads it
        if (t + 1 < NT) {
            if (t + 2 < NT) asm volatile("s_waitcnt vmcnt(4)" ::: "memory");
            else            asm volatile("s_waitcnt vmcnt(0)" ::: "memory");
        }
        __builtin_amdgcn_s_barrier();
        cb = cb + 1 == 3 ? 0 : cb + 1;
    }

    // epilogue: operand-swapped fragment = C^T layout
#pragma unroll
    for (int n = 0; n < 4; ++n) {
        const long col0 = nBase + wc * 64 + n * 16 + kg * 4;
        const f32x4 bv4 = *(const f32x4*)(bias + col0);
#pragma unroll
        for (int m = 0; m < 4; ++m) {
            const long row = mBase + wr * 64 + m * 16 + lr;
            const long idx = row * N + col0;
            if (GELU) {
                s16x4 o;
#pragma unroll
                for (int r = 0; r < 4; ++r)
                    o[r] = f2bf(gelu_fast(acc[m][n][r] + bv4[r]));
                *(s16x4*)((short*)Cout + idx) = o;
            } else {
                const f32x4 rv = *(const f32x4*)(res + idx);
                f32x4 o;
#pragma unroll
                for (int r = 0; r < 4; ++r) o[r] = acc[m][n][r] + bv4[r] + rv[r];
                *(f32x4*)((float*)Cout + idx) = o;
            }
        }
    }
}

extern "C" void kernel_launch(void* const* d_in, const int* in_sizes, int n_in,
                              void* d_out, int out_size, void* d_ws, size_t ws_size,
                              hipStream_t stream) {
    const float* x    = (const float*)d_in[0];
    const float* n1g  = (const float*)d_in[1];
    const float* n1b  = (const float*)d_in[2];
    const float* sw   = (const float*)d_in[3];
    const float* sb   = (const float*)d_in[4];
    const float* n2g  = (const float*)d_in[5];
    const float* n2b  = (const float*)d_in[6];
    const float* fc1w = (const float*)d_in[7];
    const float* fc1b = (const float*)d_in[8];
    const float* fc2w = (const float*)d_in[9];
    const float* fc2b = (const float*)d_in[10];
    float* out = (float*)d_out;

    // workspace layout (bytes)
    char* ws = (char*)d_ws;
    short* xn  = (short*)ws;                      // MM*512*2    = 102,760,448  (xn, then xn2)
    short* hb  = (short*)(ws + 102760448);        // MM*2048*2   = 411,041,792
    short* w1b = (short*)(ws + 513802240);        // 2048*512*2  =   2,097,152
    short* w2b = (short*)(ws + 515899392);        // 512*2048*2  =   2,097,152

    cvt_bf16<<<4096, 256, 0, stream>>>(fc1w, w1b, 2048 * 512);
    cvt_bf16<<<4096, 256, 0, stream>>>(fc2w, w2b, 512 * 2048);

    // LN1: x -> xn (bf16)
    ln512<<<MM, 256, 0, stream>>>(x, n1g, n1b, xn);

    // spatial MLP + residual: x1 = x + y  (into d_out)
    spatial_mlp<<<dim3(324, 16), 256, 0, stream>>>(xn, x, sw, sb, out);

    // LN2: x1 -> xn2 (bf16, reuse xn buffer)
    ln512<<<MM, 256, 0, stream>>>(out, n2g, n2b, xn);

    // -------- ABLATION (within-probe A/B): V1,V2,V3 write garbage into hb,
    // V0 (real) runs LAST and overwrites every element of hb. --------
    gemm128<512, 2048, true, 1><<<dim3(16, 784), 256, 0, stream>>>(xn, w1b, fc1b, nullptr, hb);
    gemm128<512, 2048, true, 2><<<dim3(16, 784), 256, 0, stream>>>(xn, w1b, fc1b, nullptr, hb);
    gemm128<512, 2048, true, 3><<<dim3(16, 784), 256, 0, stream>>>(xn, w1b, fc1b, nullptr, hb);
    gemm128<512, 2048, true, 0><<<dim3(16, 784), 256, 0, stream>>>(xn, w1b, fc1b, nullptr, hb);

    // FC2 + bias + residual -> out (f32, reads x1 from d_out in place)
    gemm128<2048, 512, false, 0><<<dim3(4, 784), 256, 0, stream>>>(hb, w2b, fc2b, out, out);
}

// Round 10
// 1252.395 us; speedup vs baseline: 1.8231x; 1.8231x over previous
//
#include <hip/hip_runtime.h>

#define HH 56
#define WW 56
#define CC 512
#define BB 32
#define LL (HH*WW)
#define MM (BB*LL)     // 100352 tokens
#define HID 2048

typedef __attribute__((ext_vector_type(8))) __bf16 bf16x8;
typedef __attribute__((ext_vector_type(4))) float f32x4;
typedef __attribute__((ext_vector_type(4))) short s16x4;

__device__ __forceinline__ short f2bf(float f) {
    union { float f; unsigned u; } c; c.f = f;
    unsigned r = c.u + 0x7fffu + ((c.u >> 16) & 1u);   // round-to-nearest-even
    return (short)(r >> 16);
}
__device__ __forceinline__ float bf2f(short s) {
    union { unsigned u; float f; } c; c.u = ((unsigned)(unsigned short)s) << 16;
    return c.f;
}

// fast gelu: v * t/(t+1), t = e^{2*0.7978845608*(v+0.044715 v^3)}
__device__ __forceinline__ float gelu_fast(float v) {
    float xg = 0.7978845608f * (v + 0.044715f * v * v * v);
    xg = fminf(xg, 15.0f);
    float t = __expf(2.0f * xg);
    return v * (t / (t + 1.0f));
}

// ---------------- f32 -> bf16 weight conversion ----------------
__global__ __launch_bounds__(256) void cvt_bf16(const float* __restrict__ in,
                                                short* __restrict__ out, int n) {
    int i = blockIdx.x * 256 + threadIdx.x;
    if (i < n) out[i] = f2bf(in[i]);
}

// ---------------- LayerNorm over 512 channels, 1 row / block ----------------
__global__ __launch_bounds__(256) void ln512(const float* __restrict__ x,
                                             const float* __restrict__ g,
                                             const float* __restrict__ b,
                                             short* __restrict__ out) {
    const int row = blockIdx.x;
    const int t = threadIdx.x;
    const float2 v = ((const float2*)(x + (long)row * 512))[t];
    float s = v.x + v.y;
    float q = v.x * v.x + v.y * v.y;
#pragma unroll
    for (int off = 32; off > 0; off >>= 1) {
        s += __shfl_xor(s, off, 64);
        q += __shfl_xor(q, off, 64);
    }
    __shared__ float red[8];
    const int wv = t >> 6;
    if ((t & 63) == 0) { red[wv] = s; red[4 + wv] = q; }
    __syncthreads();
    s = red[0] + red[1] + red[2] + red[3];
    q = red[4] + red[5] + red[6] + red[7];
    const float mu = s * (1.0f / 512.0f);
    const float rs = rsqrtf(q * (1.0f / 512.0f) - mu * mu + 1e-5f);
    const float2 gv = ((const float2*)g)[t];
    const float2 bv = ((const float2*)b)[t];
    const float y0 = (v.x - mu) * rs * gv.x + bv.x;
    const float y1 = (v.y - mu) * rs * gv.y + bv.y;
    union { short s2[2]; unsigned u; } o;
    o.s2[0] = f2bf(y0); o.s2[1] = f2bf(y1);
    ((unsigned*)out)[(long)row * 256 + t] = o.u;
}

// ---------------- spatial (window) MLP + residual ----------------
__global__ __launch_bounds__(256) void spatial_mlp(const short* __restrict__ xn,
                                                   const float* __restrict__ x,
                                                   const float* __restrict__ sw,
                                                   const float* __restrict__ sb,
                                                   float* x1) {
    const int head = blockIdx.y;
    const int t = threadIdx.x;
    const int ch = t & 31;
    const int wloc = t >> 5;
    const int win = blockIdx.x * 8 + wloc;        // 0..2591
    const int b = win / 81;
    const int rr = win - b * 81;
    const int wi = rr / 9;
    const int wj = rr - wi * 9;
    const int c = head * 32 + ch;

    float xv[49];
#pragma unroll
    for (int j = 0; j < 49; j++) {
        const int pr = wi * 7 + j / 7 - 4;        // padded row - P_T
        const int pc = wj * 7 + j % 7 - 4;        // padded col - P_L
        float v = 0.0f;
        if (pr >= 0 && pr < 56 && pc >= 0 && pc < 56)
            v = bf2f(xn[((long)((b * 56 + pr) * 56 + pc)) * 512 + c]);
        xv[j] = v;
    }

    const float* swh = sw + head * 2401;
    const float* sbh = sb + head * 49;

#pragma unroll 1
    for (int t7 = 0; t7 < 7; t7++) {
        float acc[7];
#pragma unroll
        for (int ii = 0; ii < 7; ii++) acc[ii] = sbh[t7 * 7 + ii];
#pragma unroll
        for (int ii = 0; ii < 7; ii++) {
            const float* swr = swh + (t7 * 7 + ii) * 49;
#pragma unroll
            for (int j = 0; j < 49; j++)
                acc[ii] = fmaf(swr[j], xv[j], acc[ii]);
        }
        const int pr = wi * 7 + t7 - 4;
        if (pr >= 0 && pr < 56) {
#pragma unroll
            for (int ii = 0; ii < 7; ii++) {
                const int pc = wj * 7 + ii - 4;
                if (pc >= 0 && pc < 56) {
                    const long idx = ((long)((b * 56 + pr) * 56 + pc)) * 512 + c;
                    x1[idx] = x[idx] + acc[ii];
                }
            }
        }
    }
}

// ---------------- 128x128 4-wave bf16 GEMM, ring-3 counted-vmcnt -------------
// r5 structure, compiler-freedom edition (r9 ablation: skeleton=76%, and
// VALUBusy 42% = ~4.5x the source-implied VALU):
//  * K-loop hand-unrolled x3, literal ring slots, POINTER-INCREMENT global
//    addressing (+32/tile) -> minimal per-tile address VALU.
//  * NO lgkmcnt(0) asm, NO setprio: compiler emits fine-grained lgkmcnt and
//    interleaves ds_read with MFMA (m97 behavior; m190: setprio hurts
//    lockstep GEMM).
//  * KEEP: counted vmcnt(4) before the single per-tile s_barrier (cross-wave
//    staging validity), T1 XCD remap, zero-conflict XOR swizzle, vectorized
//    operand-swapped epilogue.
template <int K, int N, bool GELU>
__global__ __launch_bounds__(256, 3) void gemm128(const short* __restrict__ A,
                                                  const short* __restrict__ Bw,
                                                  const float* __restrict__ bias,
                                                  const float* res,
                                                  void* Cout) {
    __shared__ __attribute__((aligned(16))) short S[24576];  // 48 KB
    const int tid = threadIdx.x;
    const int lane = tid & 63;
    const int wid = tid >> 6;
    const int wr = wid >> 1;          // 0..1  M-half (64 rows)
    const int wc = wid & 1;           // 0..1  N-half (64 cols)
    const int lr = lane & 15;
    const int kg = (lane >> 4) & 3;

    // T1: bijective XCD-aware remap (nwg % 8 == 0)
    const int gx = gridDim.x;
    const int lin = blockIdx.y * gx + blockIdx.x;
    const int cpx = (gx * gridDim.y) >> 3;
    const int orig = (lin & 7) * cpx + (lin >> 3);
    const long mBase = (long)(orig / gx) * 128;
    const long nBase = (long)(orig % gx) * 128;

    // staging sources (pre-swizzled K-chunk, key=(row>>1)&3); advanced +32/tile
    const int sRow = tid >> 2;                        // 0..63
    const int sChunk = (tid & 3) ^ ((tid >> 3) & 3);
    const short* aP0 = A + (mBase + sRow) * K + sChunk * 8;
    const short* aP1 = A + (mBase + 64 + sRow) * K + sChunk * 8;
    const short* bP0 = Bw + (nBase + sRow) * K + sChunk * 8;
    const short* bP1 = Bw + (nBase + 64 + sRow) * K + sChunk * 8;

#define GLL(src, dst)                                                           \
    __builtin_amdgcn_global_load_lds(                                           \
        (const __attribute__((address_space(1))) void*)(src),                   \
        (__attribute__((address_space(3))) void*)(dst), 16, 0, 0)

    // stage current pointers into ring slot SLOT (literal)
#define STAGE(SLOT) do {                                                        \
        char* Ad_ = (char*)S + (SLOT) * 8192 + tid * 16;                        \
        char* Bd_ = (char*)S + 24576 + (SLOT) * 8192 + tid * 16;                \
        GLL(aP0, Ad_); GLL(aP1, Ad_ + 4096);                                    \
        GLL(bP0, Bd_); GLL(bP1, Bd_ + 4096);                                    \
    } while (0)

#define ADV() do { aP0 += 32; aP1 += 32; bP0 += 32; bP1 += 32; } while (0)

    // fragment LDS byte offsets: row*64 + (kg^((row>>1)&3))*16, row = lr
    const int swzc = kg ^ ((lr >> 1) & 3);
    const int aOff = (wr * 64 + lr) * 64 + swzc * 16;    // + m*1024, m=0..3
    const int bOff = (wc * 64 + lr) * 64 + swzc * 16;    // + n*1024, n=0..3

    f32x4 acc[4][4] = {};
    const int NT = K / 32;
    static_assert(K % 96 == 32, "NT must be 1 mod 3");

    STAGE(0); ADV();
    STAGE(1); ADV();                                  // pointers now at tile 2
    asm volatile("s_waitcnt vmcnt(4)" ::: "memory");  // tile 0 landed
    __builtin_amdgcn_s_barrier();

    int t = 0;
    // one K-tile: read slot RB (literal), stage tile t+2 into slot SB (literal)
#define GTILE(RB, SB) do {                                                      \
        const char* Ab_ = (const char*)S + (RB) * 8192;                         \
        const char* Bb_ = (const char*)S + 24576 + (RB) * 8192;                 \
        bf16x8 af[4], bfv[4];                                                   \
        _Pragma("unroll")                                                       \
        for (int m = 0; m < 4; ++m) af[m] = *(const bf16x8*)(Ab_ + aOff + m * 1024); \
        _Pragma("unroll")                                                       \
        for (int n = 0; n < 4; ++n) bfv[n] = *(const bf16x8*)(Bb_ + bOff + n * 1024); \
        if (t + 2 < NT) STAGE(SB);                                              \
        ADV();                                                                  \
        _Pragma("unroll")                                                       \
        for (int m = 0; m < 4; ++m)                                             \
            _Pragma("unroll")                                                   \
            for (int n = 0; n < 4; ++n)                                         \
                acc[m][n] = __builtin_amdgcn_mfma_f32_16x16x32_bf16(bfv[n], af[m], acc[m][n], 0, 0, 0); \
        if (t + 2 < NT)      asm volatile("s_waitcnt vmcnt(4)" ::: "memory");   \
        else if (t + 1 < NT) asm volatile("s_waitcnt vmcnt(0)" ::: "memory");   \
        __builtin_amdgcn_s_barrier();                                           \
        ++t;                                                                    \
    } while (0)

    for (int g = 0; g < NT / 3; ++g) {                // NT = 16 or 64 (both 1 mod 3)
        GTILE(0, 2);
        GTILE(1, 0);
        GTILE(2, 1);
    }
    GTILE(0, 2);                                      // final tile (no stage)
#undef GTILE
#undef STAGE
#undef ADV
#undef GLL

    // epilogue: operand-swapped fragment = C^T layout:
    //   C row  = mBase + wr*64 + m*16 + lr
    //   C cols = nBase + wc*64 + n*16 + kg*4 + (0..3)   (consecutive)
#pragma unroll
    for (int n = 0; n < 4; ++n) {
        const long col0 = nBase + wc * 64 + n * 16 + kg * 4;
        const f32x4 bv4 = *(const f32x4*)(bias + col0);
#pragma unroll
        for (int m = 0; m < 4; ++m) {
            const long row = mBase + wr * 64 + m * 16 + lr;
            const long idx = row * N + col0;
            if (GELU) {
                s16x4 o;
#pragma unroll
                for (int r = 0; r < 4; ++r)
                    o[r] = f2bf(gelu_fast(acc[m][n][r] + bv4[r]));
                *(s16x4*)((short*)Cout + idx) = o;
            } else {
                const f32x4 rv = *(const f32x4*)(res + idx);
                f32x4 o;
#pragma unroll
                for (int r = 0; r < 4; ++r) o[r] = acc[m][n][r] + bv4[r] + rv[r];
                *(f32x4*)((float*)Cout + idx) = o;
            }
        }
    }
}

extern "C" void kernel_launch(void* const* d_in, const int* in_sizes, int n_in,
                              void* d_out, int out_size, void* d_ws, size_t ws_size,
                              hipStream_t stream) {
    const float* x    = (const float*)d_in[0];
    const float* n1g  = (const float*)d_in[1];
    const float* n1b  = (const float*)d_in[2];
    const float* sw   = (const float*)d_in[3];
    const float* sb   = (const float*)d_in[4];
    const float* n2g  = (const float*)d_in[5];
    const float* n2b  = (const float*)d_in[6];
    const float* fc1w = (const float*)d_in[7];
    const float* fc1b = (const float*)d_in[8];
    const float* fc2w = (const float*)d_in[9];
    const float* fc2b = (const float*)d_in[10];
    float* out = (float*)d_out;

    // workspace layout (bytes)
    char* ws = (char*)d_ws;
    short* xn  = (short*)ws;                      // MM*512*2    = 102,760,448  (xn, then xn2)
    short* hb  = (short*)(ws + 102760448);        // MM*2048*2   = 411,041,792
    short* w1b = (short*)(ws + 513802240);        // 2048*512*2  =   2,097,152
    short* w2b = (short*)(ws + 515899392);        // 512*2048*2  =   2,097,152

    cvt_bf16<<<4096, 256, 0, stream>>>(fc1w, w1b, 2048 * 512);
    cvt_bf16<<<4096, 256, 0, stream>>>(fc2w, w2b, 512 * 2048);

    // LN1: x -> xn (bf16)
    ln512<<<MM, 256, 0, stream>>>(x, n1g, n1b, xn);

    // spatial MLP + residual: x1 = x + y  (into d_out)
    spatial_mlp<<<dim3(324, 16), 256, 0, stream>>>(xn, x, sw, sb, out);

    // LN2: x1 -> xn2 (bf16, reuse xn buffer)
    ln512<<<MM, 256, 0, stream>>>(out, n2g, n2b, xn);

    // FC1 + gelu -> h (bf16)   grid: 16 N-tiles x 784 M-tiles
    gemm128<512, 2048, true><<<dim3(16, 784), 256, 0, stream>>>(xn, w1b, fc1b, nullptr, hb);

    // FC2 + bias + residual -> out (f32, reads x1 from d_out in place)
    gemm128<2048, 512, false><<<dim3(4, 784), 256, 0, stream>>>(hb, w2b, fc2b, out, out);
}

// Round 11
// 1176.044 us; speedup vs baseline: 1.9415x; 1.0649x over previous
//
#include <hip/hip_runtime.h>

#define HH 56
#define WW 56
#define CC 512
#define BB 32
#define LL (HH*WW)
#define MM (BB*LL)     // 100352 tokens
#define HID 2048

typedef __attribute__((ext_vector_type(8))) __bf16 bf16x8;
typedef __attribute__((ext_vector_type(4))) float f32x4;
typedef __attribute__((ext_vector_type(4))) short s16x4;

__device__ __forceinline__ short f2bf(float f) {
    union { float f; unsigned u; } c; c.f = f;
    unsigned r = c.u + 0x7fffu + ((c.u >> 16) & 1u);   // round-to-nearest-even
    return (short)(r >> 16);
}
__device__ __forceinline__ float bf2f(short s) {
    union { unsigned u; float f; } c; c.u = ((unsigned)(unsigned short)s) << 16;
    return c.f;
}

// fast gelu: v * t/(t+1), t = e^{2*0.7978845608*(v+0.044715 v^3)}
__device__ __forceinline__ float gelu_fast(float v) {
    float xg = 0.7978845608f * (v + 0.044715f * v * v * v);
    xg = fminf(xg, 15.0f);
    float t = __expf(2.0f * xg);
    return v * (t / (t + 1.0f));
}

// ---------------- f32 -> bf16 weight conversion ----------------
__global__ __launch_bounds__(256) void cvt_bf16(const float* __restrict__ in,
                                                short* __restrict__ out, int n) {
    int i = blockIdx.x * 256 + threadIdx.x;
    if (i < n) out[i] = f2bf(in[i]);
}

// ---------------- LayerNorm over 512 channels, 1 row / block ----------------
__global__ __launch_bounds__(256) void ln512(const float* __restrict__ x,
                                             const float* __restrict__ g,
                                             const float* __restrict__ b,
                                             short* __restrict__ out) {
    const int row = blockIdx.x;
    const int t = threadIdx.x;
    const float2 v = ((const float2*)(x + (long)row * 512))[t];
    float s = v.x + v.y;
    float q = v.x * v.x + v.y * v.y;
#pragma unroll
    for (int off = 32; off > 0; off >>= 1) {
        s += __shfl_xor(s, off, 64);
        q += __shfl_xor(q, off, 64);
    }
    __shared__ float red[8];
    const int wv = t >> 6;
    if ((t & 63) == 0) { red[wv] = s; red[4 + wv] = q; }
    __syncthreads();
    s = red[0] + red[1] + red[2] + red[3];
    q = red[4] + red[5] + red[6] + red[7];
    const float mu = s * (1.0f / 512.0f);
    const float rs = rsqrtf(q * (1.0f / 512.0f) - mu * mu + 1e-5f);
    const float2 gv = ((const float2*)g)[t];
    const float2 bv = ((const float2*)b)[t];
    const float y0 = (v.x - mu) * rs * gv.x + bv.x;
    const float y1 = (v.y - mu) * rs * gv.y + bv.y;
    union { short s2[2]; unsigned u; } o;
    o.s2[0] = f2bf(y0); o.s2[1] = f2bf(y1);
    ((unsigned*)out)[(long)row * 256 + t] = o.u;
}

// ---------------- spatial (window) MLP + residual ----------------
__global__ __launch_bounds__(256) void spatial_mlp(const short* __restrict__ xn,
                                                   const float* __restrict__ x,
                                                   const float* __restrict__ sw,
                                                   const float* __restrict__ sb,
                                                   float* x1) {
    const int head = blockIdx.y;
    const int t = threadIdx.x;
    const int ch = t & 31;
    const int wloc = t >> 5;
    const int win = blockIdx.x * 8 + wloc;        // 0..2591
    const int b = win / 81;
    const int rr = win - b * 81;
    const int wi = rr / 9;
    const int wj = rr - wi * 9;
    const int c = head * 32 + ch;

    float xv[49];
#pragma unroll
    for (int j = 0; j < 49; j++) {
        const int pr = wi * 7 + j / 7 - 4;        // padded row - P_T
        const int pc = wj * 7 + j % 7 - 4;        // padded col - P_L
        float v = 0.0f;
        if (pr >= 0 && pr < 56 && pc >= 0 && pc < 56)
            v = bf2f(xn[((long)((b * 56 + pr) * 56 + pc)) * 512 + c]);
        xv[j] = v;
    }

    const float* swh = sw + head * 2401;
    const float* sbh = sb + head * 49;

#pragma unroll 1
    for (int t7 = 0; t7 < 7; t7++) {
        float acc[7];
#pragma unroll
        for (int ii = 0; ii < 7; ii++) acc[ii] = sbh[t7 * 7 + ii];
#pragma unroll
        for (int ii = 0; ii < 7; ii++) {
            const float* swr = swh + (t7 * 7 + ii) * 49;
#pragma unroll
            for (int j = 0; j < 49; j++)
                acc[ii] = fmaf(swr[j], xv[j], acc[ii]);
        }
        const int pr = wi * 7 + t7 - 4;
        if (pr >= 0 && pr < 56) {
#pragma unroll
            for (int ii = 0; ii < 7; ii++) {
                const int pc = wj * 7 + ii - 4;
                if (pc >= 0 && pc < 56) {
                    const long idx = ((long)((b * 56 + pr) * 56 + pc)) * 512 + c;
                    x1[idx] = x[idx] + acc[ii];
                }
            }
        }
    }
}

// ============ 256x256 8-wave, BK=64, 4-phase K-sliced pipeline ===============
// m201-template port. A[M,K] rm, Bw[N,K] rm (B^T). 512 thr = 8 waves (2M x 4N),
// per-wave 128x64. LDS 128KB: A = [2 dbuf][2 kslice][256 rows][32 k] @0,
// B same @64KB. Per K-tile, 4 phases; phase = {ds_read frags; stage ONE
// half-tile (2 gloads); barrier; lgkmcnt(0); setprio(1); 16 MFMA; setprio(0);
// [counted vmcnt]; barrier}. Halves staged in READ ORDER (Aks0,Bks0,Aks1,Bks1)
// so each half lands a full tile before its first read; vmcnt(4) at ph2/ph4
// never waits on just-issued loads (3-half-tile flight depth, never 0 in loop).
template <int K, int N, bool GELU>
__global__ __launch_bounds__(512, 2) void gemm8p(const short* __restrict__ A,
                                                 const short* __restrict__ Bw,
                                                 const float* __restrict__ bias,
                                                 const float* res,
                                                 void* Cout) {
    __shared__ __attribute__((aligned(16))) short S[65536];   // 128 KB
    const int tid = threadIdx.x;
    const int lane = tid & 63;
    const int wid = tid >> 6;          // 0..7
    const int wm = wid >> 2;           // 0..1  M-half (128 rows)
    const int wn = wid & 3;            // 0..3  N-quarter (64 cols)
    const int lr = lane & 15;
    const int kg = (lane >> 4) & 3;
    const int swz = (kg ^ ((lr >> 1) & 3)) * 16;   // verified 0-conflict key

    // T1: bijective XCD-aware remap (nwg % 8 == 0)
    const int gx = gridDim.x;
    const int lin = blockIdx.y * gx + blockIdx.x;
    const int cpx = (gx * gridDim.y) >> 3;
    const int orig = (lin & 7) * cpx + (lin >> 3);
    const long mBase = (long)(orig / gx) * 256;
    const long nBase = (long)(orig % gx) * 256;

    // staging sources: thread -> (row = tid>>2 [0..127], chunk = tid&3),
    // global chunk pre-swizzled with key (row>>1)&3 = (tid>>3)&3.
    const int sRow = tid >> 2;
    const int sChunk = (tid & 3) ^ ((tid >> 3) & 3);
    const short* aSt = A + (mBase + sRow) * K + sChunk * 8;
    const short* bSt = Bw + (nBase + sRow) * K + sChunk * 8;

    const char* Sc = (const char*)S;
    char* Sw = (char*)S;

#define GLL(src, dst)                                                          \
    __builtin_amdgcn_global_load_lds(                                          \
        (const __attribute__((address_space(1))) void*)(src),                  \
        (__attribute__((address_space(3))) void*)(dst), 16, 0, 0)

    // stage half-tile: matrix A/B, dest buf DP (literal), kslice KS (literal)
#define STG_A(DP, KS) do {                                                     \
        char* d_ = Sw + (DP) * 32768 + (KS) * 16384 + tid * 16;                \
        GLL(aSt + (KS) * 32, d_);                                              \
        GLL(aSt + (KS) * 32 + 128L * K, d_ + 8192);                            \
    } while (0)
#define STG_B(DP, KS) do {                                                     \
        char* d_ = Sw + 65536 + (DP) * 32768 + (KS) * 16384 + tid * 16;        \
        GLL(bSt + (KS) * 32, d_);                                              \
        GLL(bSt + (KS) * 32 + 128L * K, d_ + 8192);                            \
    } while (0)

    f32x4 acc[8][4] = {};
    const int NT = K / 64;
    static_assert(K % 128 == 0 && K / 64 >= 4, "NT even, >=4");

    // phase: read frags (B optional - reused across m-half), stage, barrier,
    // lgkmcnt(0), setprio, 16 MFMA, setprio, WAITCODE, barrier.
#define PH(P, KS, MH, LOADB, STGCODE, WAITCODE) do {                           \
        const char* Ab_ = Sc + (P) * 32768 + (KS) * 16384;                     \
        const char* Bb_ = Sc + 65536 + (P) * 32768 + (KS) * 16384;             \
        if (LOADB) {                                                           \
            _Pragma("unroll")                                                  \
            for (int n = 0; n < 4; ++n)                                        \
                bq[n] = *(const bf16x8*)(Bb_ + (wn * 64 + n * 16 + lr) * 64 + swz); \
        }                                                                      \
        bf16x8 aq[4];                                                          \
        _Pragma("unroll")                                                      \
        for (int m = 0; m < 4; ++m)                                            \
            aq[m] = *(const bf16x8*)(Ab_ + (wm * 128 + ((MH) * 4 + m) * 16 + lr) * 64 + swz); \
        STGCODE;                                                               \
        __builtin_amdgcn_s_barrier();                                          \
        asm volatile("s_waitcnt lgkmcnt(0)" ::: "memory");                     \
        __builtin_amdgcn_s_setprio(1);                                         \
        _Pragma("unroll")                                                      \
        for (int m = 0; m < 4; ++m)                                            \
            _Pragma("unroll")                                                  \
            for (int n = 0; n < 4; ++n)                                        \
                acc[(MH) * 4 + m][n] = __builtin_amdgcn_mfma_f32_16x16x32_bf16(\
                    bq[n], aq[m], acc[(MH) * 4 + m][n], 0, 0, 0);              \
        __builtin_amdgcn_s_setprio(0);                                         \
        WAITCODE;                                                              \
        __builtin_amdgcn_s_barrier();                                          \
    } while (0)

    // one K-tile, dbuf parity P (literal); STG literal 0/1
#define GT(P, STG) do {                                                        \
        bf16x8 bq[4];                                                          \
        PH(P, 0, 0, 1, if (STG) STG_A(1 - (P), 0), );                          \
        PH(P, 0, 1, 0, if (STG) STG_B(1 - (P), 0),                             \
           if (STG) { asm volatile("s_waitcnt vmcnt(4)" ::: "memory"); }       \
           else     { asm volatile("s_waitcnt vmcnt(0)" ::: "memory"); });     \
        PH(P, 1, 0, 1, if (STG) STG_A(1 - (P), 1), );                          \
        PH(P, 1, 1, 0, if (STG) { STG_B(1 - (P), 1); aSt += 64; bSt += 64; },  \
           if (STG) { asm volatile("s_waitcnt vmcnt(4)" ::: "memory"); });     \
    } while (0)

    // prologue: tile 0's 4 halves in read order; ks0 landed, ks1 in flight
    STG_A(0, 0); STG_B(0, 0); STG_A(0, 1); STG_B(0, 1);
    aSt += 64; bSt += 64;
    asm volatile("s_waitcnt vmcnt(4)" ::: "memory");
    __builtin_amdgcn_s_barrier();

#pragma unroll 1
    for (int g = 0; g < (NT - 2) / 2; ++g) {
        GT(0, 1);
        GT(1, 1);
    }
    GT(0, 1);      // t = NT-2: stages tile NT-1 into buf 1
    GT(1, 0);      // t = NT-1: tail, no staging
#undef GT
#undef PH
#undef STG_A
#undef STG_B
#undef GLL

    // epilogue: operand-swapped fragment = C^T layout:
    //   C row  = mBase + wm*128 + m*16 + lr
    //   C cols = nBase + wn*64 + n*16 + kg*4 + (0..3)   (consecutive)
#pragma unroll
    for (int n = 0; n < 4; ++n) {
        const long col0 = nBase + wn * 64 + n * 16 + kg * 4;
        const f32x4 bv4 = *(const f32x4*)(bias + col0);
#pragma unroll
        for (int m = 0; m < 8; ++m) {
            const long row = mBase + wm * 128 + m * 16 + lr;
            const long idx = row * N + col0;
            if (GELU) {
                s16x4 o;
#pragma unroll
                for (int r = 0; r < 4; ++r)
                    o[r] = f2bf(gelu_fast(acc[m][n][r] + bv4[r]));
                *(s16x4*)((short*)Cout + idx) = o;
            } else {
                const f32x4 rv = *(const f32x4*)(res + idx);
                f32x4 o;
#pragma unroll
                for (int r = 0; r < 4; ++r) o[r] = acc[m][n][r] + bv4[r] + rv[r];
                *(f32x4*)((float*)Cout + idx) = o;
            }
        }
    }
}

extern "C" void kernel_launch(void* const* d_in, const int* in_sizes, int n_in,
                              void* d_out, int out_size, void* d_ws, size_t ws_size,
                              hipStream_t stream) {
    const float* x    = (const float*)d_in[0];
    const float* n1g  = (const float*)d_in[1];
    const float* n1b  = (const float*)d_in[2];
    const float* sw   = (const float*)d_in[3];
    const float* sb   = (const float*)d_in[4];
    const float* n2g  = (const float*)d_in[5];
    const float* n2b  = (const float*)d_in[6];
    const float* fc1w = (const float*)d_in[7];
    const float* fc1b = (const float*)d_in[8];
    const float* fc2w = (const float*)d_in[9];
    const float* fc2b = (const float*)d_in[10];
    float* out = (float*)d_out;

    // workspace layout (bytes)
    char* ws = (char*)d_ws;
    short* xn  = (short*)ws;                      // MM*512*2    = 102,760,448  (xn, then xn2)
    short* hb  = (short*)(ws + 102760448);        // MM*2048*2   = 411,041,792
    short* w1b = (short*)(ws + 513802240);        // 2048*512*2  =   2,097,152
    short* w2b = (short*)(ws + 515899392);        // 512*2048*2  =   2,097,152

    cvt_bf16<<<4096, 256, 0, stream>>>(fc1w, w1b, 2048 * 512);
    cvt_bf16<<<4096, 256, 0, stream>>>(fc2w, w2b, 512 * 2048);

    // LN1: x -> xn (bf16)
    ln512<<<MM, 256, 0, stream>>>(x, n1g, n1b, xn);

    // spatial MLP + residual: x1 = x + y  (into d_out)
    spatial_mlp<<<dim3(324, 16), 256, 0, stream>>>(xn, x, sw, sb, out);

    // LN2: x1 -> xn2 (bf16, reuse xn buffer)
    ln512<<<MM, 256, 0, stream>>>(out, n2g, n2b, xn);

    // FC1 + gelu -> h (bf16)   grid: 8 N-tiles x 392 M-tiles (256^2 tiles)
    gemm8p<512, 2048, true><<<dim3(8, 392), 512, 0, stream>>>(xn, w1b, fc1b, nullptr, hb);

    // FC2 + bias + residual -> out (f32, reads x1 from d_out in place)
    gemm8p<2048, 512, false><<<dim3(2, 392), 512, 0, stream>>>(hb, w2b, fc2b, out, out);
}

// Round 12
// 1067.424 us; speedup vs baseline: 2.1391x; 1.1018x over previous
//
#include <hip/hip_runtime.h>

#define HH 56
#define WW 56
#define CC 512
#define BB 32
#define LL (HH*WW)
#define MM (BB*LL)     // 100352 tokens
#define HID 2048

typedef __attribute__((ext_vector_type(8))) __bf16 bf16x8;
typedef __attribute__((ext_vector_type(4))) float f32x4;
typedef __attribute__((ext_vector_type(4))) short s16x4;

__device__ __forceinline__ short f2bf(float f) {
    union { float f; unsigned u; } c; c.f = f;
    unsigned r = c.u + 0x7fffu + ((c.u >> 16) & 1u);   // round-to-nearest-even
    return (short)(r >> 16);
}
__device__ __forceinline__ float bf2f(short s) {
    union { unsigned u; float f; } c; c.u = ((unsigned)(unsigned short)s) << 16;
    return c.f;
}

// fast gelu: v * t/(t+1), t = e^{2*0.7978845608*(v+0.044715 v^3)}
__device__ __forceinline__ float gelu_fast(float v) {
    float xg = 0.7978845608f * (v + 0.044715f * v * v * v);
    xg = fminf(xg, 15.0f);
    float t = __expf(2.0f * xg);
    return v * (t / (t + 1.0f));
}

// ---------------- f32 -> bf16 weight conversion ----------------
__global__ __launch_bounds__(256) void cvt_bf16(const float* __restrict__ in,
                                                short* __restrict__ out, int n) {
    int i = blockIdx.x * 256 + threadIdx.x;
    if (i < n) out[i] = f2bf(in[i]);
}

// -------- LayerNorm over 512 channels, 2 rows / block, float4 loads ---------
__global__ __launch_bounds__(256) void ln512v(const float* __restrict__ x,
                                              const float* __restrict__ g,
                                              const float* __restrict__ b,
                                              short* __restrict__ out) {
    const int t = threadIdx.x;
    const int rsel = t >> 7;                       // 0..1 row within block
    const int col = t & 127;                       // float4 column
    const long row = (long)blockIdx.x * 2 + rsel;
    const f32x4 v = ((const f32x4*)(x + row * 512))[col];
    float s = v[0] + v[1] + v[2] + v[3];
    float q = v[0]*v[0] + v[1]*v[1] + v[2]*v[2] + v[3]*v[3];
#pragma unroll
    for (int off = 32; off > 0; off >>= 1) {
        s += __shfl_xor(s, off, 64);
        q += __shfl_xor(q, off, 64);
    }
    __shared__ float red[8];
    const int wv = t >> 6;                         // 0..3 (waves 0,1=row0; 2,3=row1)
    if ((t & 63) == 0) { red[wv] = s; red[4 + wv] = q; }
    __syncthreads();
    s = red[rsel * 2] + red[rsel * 2 + 1];
    q = red[4 + rsel * 2] + red[4 + rsel * 2 + 1];
    const float mu = s * (1.0f / 512.0f);
    const float rs = rsqrtf(q * (1.0f / 512.0f) - mu * mu + 1e-5f);
    const f32x4 gv = ((const f32x4*)g)[col];
    const f32x4 bv = ((const f32x4*)b)[col];
    s16x4 o;
#pragma unroll
    for (int r = 0; r < 4; ++r)
        o[r] = f2bf((v[r] - mu) * rs * gv[r] + bv[r]);
    *(s16x4*)(out + row * 512 + col * 4) = o;
}

// ------- spatial (window) MLP + residual, 2 channels / thread ---------------
// block = 16 windows x 16 channel-pairs (one head); ushort2/float2 vectorized.
__global__ __launch_bounds__(256) void spatial_mlp(const short* __restrict__ xn,
                                                   const float* __restrict__ x,
                                                   const float* __restrict__ sw,
                                                   const float* __restrict__ sb,
                                                   float* x1) {
    const int head = blockIdx.y;
    const int t = threadIdx.x;
    const int chp = t & 15;                       // channel pair 0..15
    const int wloc = t >> 4;                      // 0..15 windows
    const int win = blockIdx.x * 16 + wloc;       // 0..2591
    const int b = win / 81;
    const int rr = win - b * 81;
    const int wi = rr / 9;
    const int wj = rr - wi * 9;
    const int c = head * 32 + chp * 2;

    // load the 49 (possibly zero-padded) window input pairs into registers
    float2 xv[49];
#pragma unroll
    for (int j = 0; j < 49; j++) {
        const int pr = wi * 7 + j / 7 - 4;        // padded row - P_T
        const int pc = wj * 7 + j % 7 - 4;        // padded col - P_L
        float2 v = {0.0f, 0.0f};
        if (pr >= 0 && pr < 56 && pc >= 0 && pc < 56) {
            const long idx = ((long)((b * 56 + pr) * 56 + pc)) * 512 + c;
            const ushort2 u = *(const ushort2*)(xn + idx);
            v.x = bf2f((short)u.x);
            v.y = bf2f((short)u.y);
        }
        xv[j] = v;
    }

    const float* swh = sw + head * 2401;
    const float* sbh = sb + head * 49;

#pragma unroll 1
    for (int t7 = 0; t7 < 7; t7++) {
        float2 acc[7];
#pragma unroll
        for (int ii = 0; ii < 7; ii++) {
            const float bb = sbh[t7 * 7 + ii];
            acc[ii].x = bb; acc[ii].y = bb;
        }
#pragma unroll
        for (int ii = 0; ii < 7; ii++) {
            const float* swr = swh + (t7 * 7 + ii) * 49;
#pragma unroll
            for (int j = 0; j < 49; j++) {
                acc[ii].x = fmaf(swr[j], xv[j].x, acc[ii].x);
                acc[ii].y = fmaf(swr[j], xv[j].y, acc[ii].y);
            }
        }
        const int pr = wi * 7 + t7 - 4;
        if (pr >= 0 && pr < 56) {
#pragma unroll
            for (int ii = 0; ii < 7; ii++) {
                const int pc = wj * 7 + ii - 4;
                if (pc >= 0 && pc < 56) {
                    const long idx = ((long)((b * 56 + pr) * 56 + pc)) * 512 + c;
                    const float2 rv = *(const float2*)(x + idx);
                    float2 o; o.x = rv.x + acc[ii].x; o.y = rv.y + acc[ii].y;
                    *(float2*)(x1 + idx) = o;
                }
            }
        }
    }
}

// ---------------- 128x128 4-wave bf16 GEMM, ring-3 counted-vmcnt -------------
// r5 VERBATIM (session-best GEMM: 418 us). A[M,K] rm, Bw[N,K] rm (B^T). BK=32.
// Ring-3 48 KB -> 3 blocks/CU. Per K-tile: stage(t+2); 8x ds_read_b128;
// lgkmcnt(0); setprio(1); 16 MFMA; setprio(0); counted vmcnt(4); ONE s_barrier.
template <int K, int N, bool GELU>
__global__ __launch_bounds__(256, 3) void gemm128(const short* __restrict__ A,
                                                  const short* __restrict__ Bw,
                                                  const float* __restrict__ bias,
                                                  const float* res,
                                                  void* Cout) {
    __shared__ __attribute__((aligned(16))) short S[24576];  // 48 KB
    const int tid = threadIdx.x;
    const int lane = tid & 63;
    const int wid = tid >> 6;
    const int wr = wid >> 1;          // 0..1  M-half (64 rows)
    const int wc = wid & 1;           // 0..1  N-half (64 cols)
    const int lr = lane & 15;
    const int kg = (lane >> 4) & 3;

    // T1: bijective XCD-aware remap (nwg % 8 == 0)
    const int gx = gridDim.x;
    const int lin = blockIdx.y * gx + blockIdx.x;
    const int cpx = (gx * gridDim.y) >> 3;
    const int orig = (lin & 7) * cpx + (lin >> 3);
    const long mBase = (long)(orig / gx) * 128;
    const long nBase = (long)(orig % gx) * 128;

    // staging source (per-thread, fixed): pre-swizzled K-chunk.
    const int sRow = tid >> 2;                        // 0..63
    const int sChunk = (tid & 3) ^ ((tid >> 3) & 3);  // key = (row>>1)&3
    const short* aSrc0 = A + (mBase + sRow) * K + sChunk * 8;
    const short* aSrc1 = A + (mBase + 64 + sRow) * K + sChunk * 8;
    const short* bSrc0 = Bw + (nBase + sRow) * K + sChunk * 8;
    const short* bSrc1 = Bw + (nBase + 64 + sRow) * K + sChunk * 8;

    auto stage = [&](int buf, int t) {
        const long k0 = (long)t * 32;
        char* Ad = (char*)S + buf * 8192 + tid * 16;
        char* Bd = (char*)S + 24576 + buf * 8192 + tid * 16;
        __builtin_amdgcn_global_load_lds(
            (const __attribute__((address_space(1))) void*)(aSrc0 + k0),
            (__attribute__((address_space(3))) void*)Ad, 16, 0, 0);
        __builtin_amdgcn_global_load_lds(
            (const __attribute__((address_space(1))) void*)(aSrc1 + k0),
            (__attribute__((address_space(3))) void*)(Ad + 4096), 16, 0, 0);
        __builtin_amdgcn_global_load_lds(
            (const __attribute__((address_space(1))) void*)(bSrc0 + k0),
            (__attribute__((address_space(3))) void*)Bd, 16, 0, 0);
        __builtin_amdgcn_global_load_lds(
            (const __attribute__((address_space(1))) void*)(bSrc1 + k0),
            (__attribute__((address_space(3))) void*)(Bd + 4096), 16, 0, 0);
    };

    // fragment LDS byte offsets: row*64 + swizzled-chunk*16, key=(row>>1)&3
    const int swzc = kg ^ ((lr >> 1) & 3);
    const int aOff = (wr * 64 + lr) * 64 + swzc * 16;    // + m*1024, m=0..3
    const int bOff = (wc * 64 + lr) * 64 + swzc * 16;    // + n*1024, n=0..3

    f32x4 acc[4][4] = {};

    stage(0, 0); stage(1, 1);
    asm volatile("s_waitcnt vmcnt(4)" ::: "memory");     // tile 0 landed
    __builtin_amdgcn_s_barrier();

    const int NT = K / 32;
    int cb = 0;                                          // current ring slot
    for (int t = 0; t < NT; ++t) {
        if (t + 2 < NT) {
            const int sb = cb >= 1 ? cb - 1 : 2;         // (cb+2)%3
            stage(sb, t + 2);
        }
        const char* Ab = (const char*)S + cb * 8192;
        const char* Bb = (const char*)S + 24576 + cb * 8192;
        bf16x8 af[4], bf[4];
#pragma unroll
        for (int m = 0; m < 4; ++m) af[m] = *(const bf16x8*)(Ab + aOff + m * 1024);
#pragma unroll
        for (int n = 0; n < 4; ++n) bf[n] = *(const bf16x8*)(Bb + bOff + n * 1024);
        asm volatile("s_waitcnt lgkmcnt(0)" ::: "memory");
        __builtin_amdgcn_s_setprio(1);
#pragma unroll
        for (int m = 0; m < 4; ++m)
#pragma unroll
            for (int n = 0; n < 4; ++n)
                acc[m][n] = __builtin_amdgcn_mfma_f32_16x16x32_bf16(bf[n], af[m],
                                                                    acc[m][n], 0, 0, 0);
        __builtin_amdgcn_s_setprio(0);
        // boundary: buf[t+1] must be landed before next tile reads it
        if (t + 1 < NT) {
            if (t + 2 < NT) asm volatile("s_waitcnt vmcnt(4)" ::: "memory");
            else            asm volatile("s_waitcnt vmcnt(0)" ::: "memory");
        }
        __builtin_amdgcn_s_barrier();
        cb = cb + 1 == 3 ? 0 : cb + 1;
    }

    // epilogue: operand-swapped fragment = C^T layout:
    //   C row  = mBase + wr*64 + m*16 + lr
    //   C cols = nBase + wc*64 + n*16 + kg*4 + (0..3)   (consecutive)
#pragma unroll
    for (int n = 0; n < 4; ++n) {
        const long col0 = nBase + wc * 64 + n * 16 + kg * 4;
        const f32x4 bv4 = *(const f32x4*)(bias + col0);
#pragma unroll
        for (int m = 0; m < 4; ++m) {
            const long row = mBase + wr * 64 + m * 16 + lr;
            const long idx = row * N + col0;
            if (GELU) {
                s16x4 o;
#pragma unroll
                for (int r = 0; r < 4; ++r)
                    o[r] = f2bf(gelu_fast(acc[m][n][r] + bv4[r]));
                *(s16x4*)((short*)Cout + idx) = o;
            } else {
                const f32x4 rv = *(const f32x4*)(res + idx);
                f32x4 o;
#pragma unroll
                for (int r = 0; r < 4; ++r) o[r] = acc[m][n][r] + bv4[r] + rv[r];
                *(f32x4*)((float*)Cout + idx) = o;
            }
        }
    }
}

extern "C" void kernel_launch(void* const* d_in, const int* in_sizes, int n_in,
                              void* d_out, int out_size, void* d_ws, size_t ws_size,
                              hipStream_t stream) {
    const float* x    = (const float*)d_in[0];
    const float* n1g  = (const float*)d_in[1];
    const float* n1b  = (const float*)d_in[2];
    const float* sw   = (const float*)d_in[3];
    const float* sb   = (const float*)d_in[4];
    const float* n2g  = (const float*)d_in[5];
    const float* n2b  = (const float*)d_in[6];
    const float* fc1w = (const float*)d_in[7];
    const float* fc1b = (const float*)d_in[8];
    const float* fc2w = (const float*)d_in[9];
    const float* fc2b = (const float*)d_in[10];
    float* out = (float*)d_out;

    // workspace layout (bytes)
    char* ws = (char*)d_ws;
    short* xn  = (short*)ws;                      // MM*512*2    = 102,760,448  (xn, then xn2)
    short* hb  = (short*)(ws + 102760448);        // MM*2048*2   = 411,041,792
    short* w1b = (short*)(ws + 513802240);        // 2048*512*2  =   2,097,152
    short* w2b = (short*)(ws + 515899392);        // 512*2048*2  =   2,097,152

    cvt_bf16<<<4096, 256, 0, stream>>>(fc1w, w1b, 2048 * 512);
    cvt_bf16<<<4096, 256, 0, stream>>>(fc2w, w2b, 512 * 2048);

    // LN1: x -> xn (bf16), 2 rows/block float4
    ln512v<<<MM / 2, 256, 0, stream>>>(x, n1g, n1b, xn);

    // spatial MLP + residual: x1 = x + y  (into d_out), 2ch/thread
    spatial_mlp<<<dim3(162, 16), 256, 0, stream>>>(xn, x, sw, sb, out);

    // LN2: x1 -> xn2 (bf16, reuse xn buffer)
    ln512v<<<MM / 2, 256, 0, stream>>>(out, n2g, n2b, xn);

    // FC1 + gelu -> h (bf16)   grid: 16 N-tiles x 784 M-tiles
    gemm128<512, 2048, true><<<dim3(16, 784), 256, 0, stream>>>(xn, w1b, fc1b, nullptr, hb);

    // FC2 + bias + residual -> out (f32, reads x1 from d_out in place)
    gemm128<2048, 512, false><<<dim3(4, 784), 256, 0, stream>>>(hb, w2b, fc2b, out, out);
}